// Round 10
// baseline (126.849 us; speedup 1.0000x reference)
//
#include <hip/hip_runtime.h>

typedef _Float16 f16;
typedef __attribute__((ext_vector_type(4))) _Float16 f16x4;
typedef __attribute__((ext_vector_type(8))) _Float16 f16x8;
typedef __attribute__((ext_vector_type(2))) __fp16 fp16x2;
typedef __attribute__((ext_vector_type(4))) float f32x4;
typedef __attribute__((ext_vector_type(16))) float f32x16;
typedef __attribute__((ext_vector_type(2))) unsigned u32x2;

#define MFMA16(a, b, c) __builtin_amdgcn_mfma_f32_16x16x32_f16((a), (b), (c), 0, 0, 0)
#define MFMA32(a, b, c) __builtin_amdgcn_mfma_f32_32x32x16_f16((a), (b), (c), 0, 0, 0)

__device__ __forceinline__ void gload_lds16(const void* g, void* l) {
  __builtin_amdgcn_global_load_lds(
      (const __attribute__((address_space(1))) void*)g,
      (__attribute__((address_space(3))) void*)l, 16, 0, 0);
}

__device__ __forceinline__ unsigned pkrtz(float lo, float hi) {
  union { fp16x2 h; unsigned u; } cv;
  cv.h = __builtin_amdgcn_cvt_pkrtz(lo, hi);
  return cv.u;
}

// exchange halves: a' = [a.lo | b.lo_from_partner], b' = [a.hi_from_partner | b.hi]
__device__ __forceinline__ void xch(unsigned& a, unsigned& b) {
#if __has_builtin(__builtin_amdgcn_permlane32_swap)
  u32x2 r = __builtin_amdgcn_permlane32_swap(a, b, false, false);
  a = r[0];
  b = r[1];
#else
  unsigned sa = __shfl_xor((int)a, 32), sb = __shfl_xor((int)b, 32);
  bool hi = (threadIdx.x & 32) != 0;
  unsigned x = hi ? sb : a;
  unsigned y = hi ? b : sa;
  a = x;
  b = y;
#endif
}

// ------- fused prep: convert x -> f16, transpose Wqkv & Wproj -> [N][K] f16 -------
__global__ __launch_bounds__(256) void k_prep(
    const float* __restrict__ x, f16* __restrict__ xb,
    const float* __restrict__ Wq, f16* __restrict__ WqT,
    const float* __restrict__ Wp, f16* __restrict__ WpT) {
  __shared__ float tile[64][65];
  int bid = blockIdx.x;
  if (bid < 768) {
    int i = bid * 256 + threadIdx.x;
#pragma unroll
    for (int it = 0; it < 4; ++it, i += 768 * 256) {
      float4 v = ((const float4*)x)[i];
      f16x4 o;
      o[0] = (f16)v.x; o[1] = (f16)v.y; o[2] = (f16)v.z; o[3] = (f16)v.w;
      ((f16x4*)xb)[i] = o;
    }
    return;
  }
  const float* in; f16* out; int N, n0, k0;
  if (bid < 1200) {
    int t = bid - 768;
    in = Wq; out = WqT; N = 2304;
    n0 = (t % 36) * 64; k0 = (t / 36) * 64;
  } else {
    int t = bid - 1200;
    in = Wp; out = WpT; N = 768;
    n0 = (t % 12) * 64; k0 = (t / 12) * 64;
  }
  int c = threadIdx.x & 63, r4 = threadIdx.x >> 6;
#pragma unroll
  for (int i = 0; i < 16; ++i) {
    int r = i * 4 + r4;
    tile[r][c] = in[(size_t)(k0 + r) * N + n0 + c];
  }
  __syncthreads();
#pragma unroll
  for (int i = 0; i < 16; ++i) {
    int r = i * 4 + r4;
    out[(size_t)(n0 + r) * 768 + k0 + c] = (f16)tile[c][r];
  }
}

// ---------------- 128x128 f16 MFMA GEMM, A[M][K] * BT[N][K]^T ----------------
__global__ __launch_bounds__(256) void k_gemm(
    const f16* __restrict__ A, const f16* __restrict__ BT,
    int M, int N, int K, int mode,
    f16* __restrict__ Qo, f16* __restrict__ Ko, f16* __restrict__ Vt,
    const float* __restrict__ bias, float* __restrict__ out) {
  __shared__ f16 As[128 * 32];
  __shared__ f16 Bs[128 * 32];
  int tid = threadIdx.x;
  int wv = tid >> 6;
  int lane = tid & 63;
  int lr = lane & 15, lc = lane >> 4;
  int m0 = blockIdx.x * 128, n0 = blockIdx.y * 128;
  int wm = (wv >> 1) * 64, wn = (wv & 1) * 64;
  f32x4 acc[4][4] = {};
  int nK = K >> 5;
  for (int kt = 0; kt < nK; ++kt) {
    int k0 = kt << 5;
#pragma unroll
    for (int i = 0; i < 2; ++i) {
      int g = i * 256 + tid;
      gload_lds16(A + (size_t)(m0 + (g >> 2)) * K + k0 + (g & 3) * 8,
                  As + (size_t)(i * 256 + (tid & 192)) * 8);
    }
#pragma unroll
    for (int i = 0; i < 2; ++i) {
      int g = i * 256 + tid;
      gload_lds16(BT + (size_t)(n0 + (g >> 2)) * K + k0 + (g & 3) * 8,
                  Bs + (size_t)(i * 256 + (tid & 192)) * 8);
    }
    __syncthreads();
    f16x8 af[4], bf[4];
#pragma unroll
    for (int mi = 0; mi < 4; ++mi)
      af[mi] = *(const f16x8*)&As[(wm + mi * 16 + lr) * 32 + lc * 8];
#pragma unroll
    for (int ni = 0; ni < 4; ++ni)
      bf[ni] = *(const f16x8*)&Bs[(wn + ni * 16 + lr) * 32 + lc * 8];
#pragma unroll
    for (int mi = 0; mi < 4; ++mi)
#pragma unroll
      for (int ni = 0; ni < 4; ++ni)
        acc[mi][ni] = MFMA16(af[mi], bf[ni], acc[mi][ni]);
    __syncthreads();
  }
  if (mode == 0) {
#pragma unroll
    for (int ni = 0; ni < 4; ++ni) {
      int col = n0 + wn + ni * 16 + lr;
      int s = col / 768;
      int hh = (col - s * 768) >> 6;
      int d = col & 63;
      if (s == 2) {
#pragma unroll
        for (int mi = 0; mi < 4; ++mi) {
          int row0 = m0 + wm + mi * 16 + lc * 4;
          int b = row0 >> 11, t = row0 & 2047;
          f16x4 tv;
#pragma unroll
          for (int r = 0; r < 4; ++r) tv[r] = (f16)acc[mi][ni][r];
          *(f16x4*)&Vt[((size_t)(b * 12 + hh) * 64 + d) * 2048 + t] = tv;
        }
      } else {
        f16* dst = (s == 0) ? Qo : Ko;
#pragma unroll
        for (int mi = 0; mi < 4; ++mi)
#pragma unroll
          for (int r = 0; r < 4; ++r) {
            int row = m0 + wm + mi * 16 + lc * 4 + r;
            int b = row >> 11, t = row & 2047;
            dst[((size_t)(b * 12 + hh) * 2048 + t) * 64 + d] =
                (f16)acc[mi][ni][r];
          }
      }
    }
  } else {
#pragma unroll
    for (int ni = 0; ni < 4; ++ni) {
      int col = n0 + wn + ni * 16 + lr;
      float bv = bias[col];
#pragma unroll
      for (int mi = 0; mi < 4; ++mi)
#pragma unroll
        for (int r = 0; r < 4; ++r) {
          int row = m0 + wm + mi * 16 + lc * 4 + r;
          out[(size_t)row * 768 + col] = acc[mi][ni][r] + bv;
        }
    }
  }
}

// ---- causal softplus-normalized attention: swapped 32x32 MFMA, P in registers ----
// One wave (64 thr) per (bh, 32-row q-tile). q = lane&31 (both halves), hi =
// lane>>5. QK^T: S = mfma32(A=K, B=Q) -> lane holds S[key][its q] for 16 keys
// per 32-key block (key = (r&3)+8*(r>>2)+4*hi). Softplus+rowsum in-lane.
// P->f16 via cvt_pkrtz; permlane32_swap builds PV B-operand frags. PV:
// O^T = mfma32(A=Vt-frag, B=P). No LDS, no barriers, K prefetched 1 tile ahead.
__global__ __launch_bounds__(64, 2) void k_attn(const f16* __restrict__ Q,
                                                const f16* __restrict__ K,
                                                const f16* __restrict__ Vt,
                                                f16* __restrict__ Ab) {
  int lane = threadIdx.x;
  int ql = lane & 31;
  int hi = lane >> 5;
  int hi8 = hi << 3, hi4 = hi << 2;
  int bh = blockIdx.x;
  int qt = 63 - (int)blockIdx.y;  // heavy blocks dispatch first
  int qw = qt * 32;
  int b = bh / 12, h = bh - b * 12;
  const f16* Qp = Q + (size_t)bh * 2048 * 64;
  const f16* Kp = K + (size_t)bh * 2048 * 64;
  const f16* Vp = Vt + (size_t)bh * 64 * 2048;

  const f16 a16 = (f16)0.18033688f;  // 0.125 * log2(e): fold scale into Q
  f16x8 qf[4];  // Q[qw+ql][c*16+hi8 ..+8]
#pragma unroll
  for (int c = 0; c < 4; ++c) {
    qf[c] = *(const f16x8*)&Qp[(size_t)(qw + ql) * 64 + c * 16 + hi8];
    qf[c] *= a16;
  }

  f32x16 o0 = {}, o1 = {};  // O^T[d = db*32 + crow(r,hi)][q]
  float rsp[4] = {0.f, 0.f, 0.f, 0.f};
  f16x8 kf[2][4];  // K[kb+kblk*32+ql][c*16+hi8 ..+8]

  auto loadK = [&](int kb) {
#pragma unroll
    for (int kblk = 0; kblk < 2; ++kblk)
#pragma unroll
      for (int c = 0; c < 4; ++c)
        kf[kblk][c] = *(const f16x8*)&Kp[(size_t)(kb + kblk * 32 + ql) * 64 +
                                         c * 16 + hi8];
  };

  // softplus: w' = log2(1+2^z) (uniform ln2 cancels in w/rowsum), in-place.
  auto spblk = [&](f32x16& sv, bool domask) {
#pragma unroll
    for (int r = 0; r < 16; ++r) {
      float z = sv[r];
      float w = __builtin_amdgcn_logf(1.f + __builtin_amdgcn_exp2f(z));
      if (domask) {
        int kl = (r & 3) + ((r >> 2) << 3) + hi4;
        w = (kl <= ql) ? w : 0.f;
      }
      rsp[r & 3] += w;
      sv[r] = w;
    }
  };

  // pack P to f16, exchange halves, feed PV for one 32-key block
  auto pvblk = [&](f32x16& sv, f16x8 (&vfa)[2], f16x8 (&vfb)[2]) {
#pragma unroll
    for (int ks = 0; ks < 2; ++ks) {
      unsigned Aw = pkrtz(sv[ks * 8 + 0], sv[ks * 8 + 1]);
      unsigned Bw = pkrtz(sv[ks * 8 + 2], sv[ks * 8 + 3]);
      unsigned Cw = pkrtz(sv[ks * 8 + 4], sv[ks * 8 + 5]);
      unsigned Dw = pkrtz(sv[ks * 8 + 6], sv[ks * 8 + 7]);
      xch(Aw, Cw);
      xch(Bw, Dw);
      union { unsigned u[4]; f16x8 v; } pf;
      pf.u[0] = Aw; pf.u[1] = Bw; pf.u[2] = Cw; pf.u[3] = Dw;
      o0 = MFMA32(vfa[ks], pf.v, o0);
      o1 = MFMA32(vfb[ks], pf.v, o1);
    }
  };

  auto tile = [&](int kb, bool dob1, bool mask, int kbn) {
    // 1. QK^T on prefetched kf
    f32x16 s0 = {}, s1 = {};
#pragma unroll
    for (int c = 0; c < 4; ++c) s0 = MFMA32(kf[0][c], qf[c], s0);
    if (dob1) {
#pragma unroll
      for (int c = 0; c < 4; ++c) s1 = MFMA32(kf[1][c], qf[c], s1);
    }
    // 2. V loads (latency hides under softplus)
    f16x8 vf00[2], vf10[2], vf01[2], vf11[2];  // [db][kblk][ks]
#pragma unroll
    for (int ks = 0; ks < 2; ++ks) {
      vf00[ks] = *(const f16x8*)&Vp[(size_t)ql * 2048 + kb + ks * 16 + hi8];
      vf10[ks] =
          *(const f16x8*)&Vp[(size_t)(32 + ql) * 2048 + kb + ks * 16 + hi8];
    }
    if (dob1) {
#pragma unroll
      for (int ks = 0; ks < 2; ++ks) {
        vf01[ks] =
            *(const f16x8*)&Vp[(size_t)ql * 2048 + kb + 32 + ks * 16 + hi8];
        vf11[ks] = *(const f16x8*)&Vp[(size_t)(32 + ql) * 2048 + kb + 32 +
                                      ks * 16 + hi8];
      }
    }
    // 3. prefetch next tile's K (hides under softplus+PV)
    if (kbn >= 0) loadK(kbn);
    // 4. softplus (+diag mask on the last processed block) ; 5. pack + PV
    spblk(s0, mask && !dob1);
    pvblk(s0, vf00, vf10);
    if (dob1) {
      spblk(s1, mask);
      pvblk(s1, vf01, vf11);
    }
  };

  int dt = qt >> 1;        // diagonal 64-tile index
  bool odd = (qt & 1);     // odd: kblk0 full, kblk1 diag; even: kblk0 diag only
  loadK(0);
  for (int kt = 0; kt < dt; ++kt) tile(kt * 64, true, false, (kt + 1) * 64);
  tile(dt * 64, odd, true, -1);

  // epilogue: rowsum across the two key-halves, normalize, store
  float rs = (rsp[0] + rsp[1]) + (rsp[2] + rsp[3]);
  rs += __shfl_xor(rs, 32);
  float inv = 1.0f / rs;
  f16* rowp = &Ab[((size_t)b * 2048 + qw + ql) * 768 + h * 64];
#pragma unroll
  for (int db = 0; db < 2; ++db) {
    const f32x16& oo = db ? o1 : o0;
#pragma unroll
    for (int g = 0; g < 4; ++g) {
      f16x4 v4;
#pragma unroll
      for (int j = 0; j < 4; ++j) v4[j] = (f16)(oo[g * 4 + j] * inv);
      *(f16x4*)&rowp[db * 32 + g * 8 + hi4] = v4;
    }
  }
}

// ---------------- host ----------------
extern "C" void kernel_launch(void* const* d_in, const int* in_sizes, int n_in,
                              void* d_out, int out_size, void* d_ws,
                              size_t ws_size, hipStream_t stream) {
  const float* x = (const float*)d_in[0];
  const float* Wqkv = (const float*)d_in[1];
  const float* Wproj = (const float*)d_in[2];
  const float* bproj = (const float*)d_in[3];
  float* out = (float*)d_out;
  char* ws = (char*)d_ws;

  f16* xb     = (f16*)(ws + 0);         // 4096x768
  f16* WqkvT  = (f16*)(ws + 6291456);   // 2304x768
  f16* WprojT = (f16*)(ws + 9830400);   // 768x768
  f16* Qb     = (f16*)(ws + 11010048);  // 24x2048x64
  f16* Kb     = (f16*)(ws + 17301504);  // 24x2048x64
  f16* Vtb    = (f16*)(ws + 23592960);  // 24x64x2048
  f16* Ab     = (f16*)(ws + 29884416);  // 4096x768
  // total 36,175,872 B

  k_prep<<<1344, 256, 0, stream>>>(x, xb, Wqkv, WqkvT, Wproj, WprojT);
  k_gemm<<<dim3(32, 18), 256, 0, stream>>>(xb, WqkvT, 4096, 2304, 768, 0, Qb,
                                           Kb, Vtb, nullptr, nullptr);
  k_attn<<<dim3(24, 64), 64, 0, stream>>>(Qb, Kb, Vtb, Ab);
  k_gemm<<<dim3(32, 6), 256, 0, stream>>>(Ab, WprojT, 4096, 768, 768, 1,
                                          nullptr, nullptr, nullptr, bproj, out);
}